// Round 1
// baseline (7295.515 us; speedup 1.0000x reference)
//
#include <hip/hip_runtime.h>
#include <math.h>

#define TOK 1024   // B*S
#define DM  512
#define SEQ 512
#define NB  2
#define CHUNK 32
#define NCH (SEQ/CHUNK)   // 16

// ---------------- embedding gather ----------------
__global__ __launch_bounds__(256) void embed_gather(
    const int* __restrict__ x,
    const float* __restrict__ t0, const float* __restrict__ t1,
    const float* __restrict__ t2, const float* __restrict__ t3,
    const float* __restrict__ t4, const float* __restrict__ t5,
    float* __restrict__ E) {
  int t = blockIdx.x;
  int tid = threadIdx.x;
  const int* xb = x + t * 6;
  for (int c = tid; c < 1216; c += 256) {
    float val;
    if (c < 128)       val = t0[xb[0]*128 + c]        * 11.313708498984761f;
    else if (c < 384)  val = t1[xb[1]*256 + (c-128)]  * 16.0f;
    else if (c < 448)  val = t2[xb[2]*64  + (c-384)]  * 8.0f;
    else if (c < 960)  val = t3[xb[3]*512 + (c-448)]  * 22.627416997969522f;
    else if (c < 1088) val = t4[xb[4]*128 + (c-960)]  * 11.313708498984761f;
    else               val = t5[xb[5]*128 + (c-1088)] * 11.313708498984761f;
    E[(size_t)t*1216 + c] = val;
  }
}

// ---------------- positional encoding add ----------------
__global__ __launch_bounds__(256) void add_pos(float* __restrict__ h) {
  int t = blockIdx.x;
  int s = t & (SEQ-1);
  int tid = threadIdx.x;
  for (int d = tid; d < DM; d += 256) {
    int k = d >> 1;
    float div = expf((float)(2*k) * (-9.210340371976184f / 512.0f));
    float ang = (float)s * div;
    h[(size_t)t*DM + d] += (d & 1) ? cosf(ang) : sinf(ang);
  }
}

// ---------------- generic fp32 GEMM + bias + activation ----------------
// ACT: 0=none, 1=elu(x)+1, 2=exact gelu
template<int ACT>
__global__ __launch_bounds__(256) void gemm_act(
    const float* __restrict__ A, const float* __restrict__ W,
    const float* __restrict__ bias, float* __restrict__ C,
    int M, int K, int N) {
  __shared__ float As[16][65];
  __shared__ float Bs[16][65];
  const int m0 = blockIdx.x * 64;
  const int n0 = blockIdx.y * 64;
  const int tid = threadIdx.x;
  const int tx = tid & 15, ty = tid >> 4;
  float acc[4][4] = {};
  for (int k0 = 0; k0 < K; k0 += 16) {
#pragma unroll
    for (int l = 0; l < 4; ++l) {
      int e = tid + l*256;
      int row = e >> 4, col = e & 15;
      As[col][row] = A[(size_t)(m0+row)*K + k0 + col];
    }
#pragma unroll
    for (int l = 0; l < 4; ++l) {
      int e = tid + l*256;
      int r = e >> 6, c = e & 63;
      Bs[r][c] = W[(size_t)(k0+r)*N + n0 + c];
    }
    __syncthreads();
#pragma unroll
    for (int kk = 0; kk < 16; ++kk) {
      float a[4], b[4];
#pragma unroll
      for (int i = 0; i < 4; ++i) a[i] = As[kk][ty*4+i];
#pragma unroll
      for (int j = 0; j < 4; ++j) b[j] = Bs[kk][tx*4+j];
#pragma unroll
      for (int i = 0; i < 4; ++i)
#pragma unroll
        for (int j = 0; j < 4; ++j) acc[i][j] += a[i]*b[j];
    }
    __syncthreads();
  }
#pragma unroll
  for (int i = 0; i < 4; ++i) {
    int row = m0 + ty*4 + i;
#pragma unroll
    for (int j = 0; j < 4; ++j) {
      int col = n0 + tx*4 + j;
      float v = acc[i][j] + bias[col];
      if (ACT == 1) v = (v > 0.0f) ? v + 1.0f : expf(v);
      if (ACT == 2) v = 0.5f * v * (1.0f + erff(v * 0.70710678118654752f));
      C[(size_t)row*N + col] = v;
    }
  }
}

// ---------------- attention pass A: per-chunk KV / K sums ----------------
__global__ __launch_bounds__(256) void attn_chunk_sums(
    const float* __restrict__ Kg, const float* __restrict__ Vg,
    float* __restrict__ kvst, float* __restrict__ ksum) {
  int ch = blockIdx.x, bh = blockIdx.y;
  int b = bh >> 3, h = bh & 7;
  __shared__ float Ks[CHUNK][64], Vs[CHUNK][64];
  int tid = threadIdx.x;
  const float* Kbase = Kg + ((size_t)(b*SEQ + ch*CHUNK))*DM + h*64;
  const float* Vbase = Vg + ((size_t)(b*SEQ + ch*CHUNK))*DM + h*64;
#pragma unroll
  for (int l = 0; l < CHUNK*64/256; ++l) {
    int e = tid + l*256;
    int r = e >> 6, c = e & 63;
    Ks[r][c] = Kbase[(size_t)r*DM + c];
    Vs[r][c] = Vbase[(size_t)r*DM + c];
  }
  __syncthreads();
  int d = tid >> 2, m0 = (tid & 3) * 16;
  float acc[16] = {};
  for (int s = 0; s < CHUNK; ++s) {
    float kd = Ks[s][d];
#pragma unroll
    for (int j = 0; j < 16; ++j) acc[j] += kd * Vs[s][m0+j];
  }
  float* dst = kvst + (((size_t)(bh*NCH + ch)*64 + d)*64) + m0;
#pragma unroll
  for (int j = 0; j < 16; ++j) dst[j] = acc[j];
  if (tid < 64) {
    float s = 0;
    for (int r = 0; r < CHUNK; ++r) s += Ks[r][tid];
    ksum[(size_t)(bh*NCH + ch)*64 + tid] = s;
  }
}

// ---------------- attention pass B: exclusive prefix over chunks ----------------
__global__ __launch_bounds__(256) void attn_scan(
    float* __restrict__ kvst, float* __restrict__ ksum) {
  int bh = blockIdx.x;
  int tid = threadIdx.x;
  for (int l = 0; l < 16; ++l) {
    int e = tid + l*256;
    float run = 0.0f;
    size_t base = (size_t)bh*NCH*4096 + e;
    for (int ch = 0; ch < NCH; ++ch) {
      size_t idx = base + (size_t)ch*4096;
      float t = kvst[idx];
      kvst[idx] = run;
      run += t;
    }
  }
  if (tid < 64) {
    float run = 0.0f;
    for (int ch = 0; ch < NCH; ++ch) {
      size_t idx = (size_t)(bh*NCH + ch)*64 + tid;
      float t = ksum[idx];
      ksum[idx] = run;
      run += t;
    }
  }
}

// ---------------- attention pass C: per-chunk output ----------------
__global__ __launch_bounds__(256) void attn_chunk_out(
    const float* __restrict__ Qg, const float* __restrict__ Kg,
    const float* __restrict__ Vg, const float* __restrict__ kvst,
    const float* __restrict__ ksum, float* __restrict__ O) {
  int ch = blockIdx.x, bh = blockIdx.y;
  int b = bh >> 3, h = bh & 7;
  __shared__ float Qs[CHUNK][64], Ks[CHUNK][64], Vs[CHUNK][64];
  __shared__ float kvp[64][64];
  __shared__ float Sl[CHUNK][CHUNK+1];
  __shared__ float ksp[64];
  __shared__ float den[CHUNK];
  int tid = threadIdx.x;
  const float* Qbase = Qg + ((size_t)(b*SEQ + ch*CHUNK))*DM + h*64;
  const float* Kbase = Kg + ((size_t)(b*SEQ + ch*CHUNK))*DM + h*64;
  const float* Vbase = Vg + ((size_t)(b*SEQ + ch*CHUNK))*DM + h*64;
#pragma unroll
  for (int l = 0; l < CHUNK*64/256; ++l) {
    int e = tid + l*256;
    int r = e >> 6, c = e & 63;
    Qs[r][c] = Qbase[(size_t)r*DM + c];
    Ks[r][c] = Kbase[(size_t)r*DM + c];
    Vs[r][c] = Vbase[(size_t)r*DM + c];
  }
  {
    const float* src = kvst + (size_t)(bh*NCH + ch)*4096;
#pragma unroll
    for (int l = 0; l < 16; ++l) {
      int e = tid + l*256;
      ((float*)kvp)[e] = src[e];
    }
  }
  if (tid < 64) ksp[tid] = ksum[(size_t)(bh*NCH + ch)*64 + tid];
  __syncthreads();
  // S = Q K^T within chunk
#pragma unroll
  for (int l = 0; l < 4; ++l) {
    int e = tid + l*256;
    int i = e >> 5, j = e & 31;
    float s = 0;
    for (int d2 = 0; d2 < 64; ++d2) s += Qs[i][d2] * Ks[j][d2];
    Sl[i][j] = s;
  }
  __syncthreads();
  if (tid < CHUNK) {
    int i = tid;
    float dsum = 0;
    for (int d2 = 0; d2 < 64; ++d2) dsum += Qs[i][d2] * ksp[d2];
    for (int j = 0; j <= i; ++j) dsum += Sl[i][j];
    den[i] = 1.0f / (dsum + 1e-6f);
  }
  __syncthreads();
  int row = tid >> 3, m0 = (tid & 7) * 8;
  float acc[8] = {};
  for (int d2 = 0; d2 < 64; ++d2) {
    float qd = Qs[row][d2];
#pragma unroll
    for (int j = 0; j < 8; ++j) acc[j] += qd * kvp[d2][m0+j];
  }
  for (int j2 = 0; j2 <= row; ++j2) {
    float sv = Sl[row][j2];
#pragma unroll
    for (int j = 0; j < 8; ++j) acc[j] += sv * Vs[j2][m0+j];
  }
  float zi = den[row];
  float* dst = O + ((size_t)(b*SEQ + ch*CHUNK + row))*DM + h*64 + m0;
#pragma unroll
  for (int j = 0; j < 8; ++j) dst[j] = acc[j] * zi;
}

// ---------------- residual + layernorm ----------------
__global__ __launch_bounds__(256) void resid_ln(
    const float* __restrict__ x, const float* __restrict__ r,
    const float* __restrict__ g, const float* __restrict__ bb,
    float* __restrict__ out) {
  int t = blockIdx.x;
  int tid = threadIdx.x;
  __shared__ float red[256];
  const float* xb = x + (size_t)t*DM;
  float v0 = xb[tid];
  float v1 = xb[tid+256];
  if (r) {
    const float* rb = r + (size_t)t*DM;
    v0 += rb[tid];
    v1 += rb[tid+256];
  }
  red[tid] = v0 + v1;
  __syncthreads();
  for (int o = 128; o > 0; o >>= 1) {
    if (tid < o) red[tid] += red[tid+o];
    __syncthreads();
  }
  float mean = red[0] * (1.0f/512.0f);
  __syncthreads();
  float d0 = v0 - mean, d1 = v1 - mean;
  red[tid] = d0*d0 + d1*d1;
  __syncthreads();
  for (int o = 128; o > 0; o >>= 1) {
    if (tid < o) red[tid] += red[tid+o];
    __syncthreads();
  }
  float rs = rsqrtf(red[0] * (1.0f/512.0f) + 1e-5f);
  out[(size_t)t*DM + tid]     = d0*rs*g[tid]     + bb[tid];
  out[(size_t)t*DM + tid+256] = d1*rs*g[tid+256] + bb[tid+256];
}

// ---------------- collapsed output heads ----------------
struct HeadPtrs {
  const float* pw[6]; const float* pb[6];
  const float* vw[6]; const float* vb[6];
};

__global__ __launch_bounds__(512) void head_u(HeadPtrs hp, float* __restrict__ U,
                                              float* __restrict__ Cc) {
  const int vsz[6] = {56, 135, 18, 87, 18, 25};
  int d = threadIdx.x;
  float acc = 0;
  for (int i = 0; i < 6; ++i) {
    const float* pwrow = hp.pw[i] + (size_t)d * vsz[i];
    const float* vwi = hp.vw[i];
    for (int j = 0; j < vsz[i]; ++j) acc += pwrow[j] * vwi[j];
  }
  U[d] = acc;
  if (d == 0) {
    float c = 0;
    for (int i = 0; i < 6; ++i) {
      float cc = hp.vb[i][0];
      for (int j = 0; j < vsz[i]; ++j) cc += hp.pb[i][j] * hp.vw[i][j];
      c += cc;
    }
    Cc[0] = c;
  }
}

__global__ __launch_bounds__(512) void final_out(
    const float* __restrict__ hf, const float* __restrict__ U,
    const float* __restrict__ Cc, float* __restrict__ out) {
  int b = blockIdx.x;
  int d = threadIdx.x;
  __shared__ float red[512];
  float cs = 0;
  const float* hb = hf + (size_t)b*SEQ*DM + d;
  for (int s = 0; s < SEQ; ++s) cs += hb[(size_t)s*DM];
  red[d] = cs * U[d];
  __syncthreads();
  for (int o = 256; o > 0; o >>= 1) {
    if (d < o) red[d] += red[d+o];
    __syncthreads();
  }
  if (d == 0) out[b] = (red[0] * (1.0f/512.0f) + Cc[0]) * (1.0f/6.0f);
}

// ---------------- launch ----------------
extern "C" void kernel_launch(void* const* d_in, const int* in_sizes, int n_in,
                              void* d_out, int out_size, void* d_ws, size_t ws_size,
                              hipStream_t stream) {
  const int*   x    = (const int*)d_in[0];
  const float* T0   = (const float*)d_in[1];
  const float* T1   = (const float*)d_in[2];
  const float* T2   = (const float*)d_in[3];
  const float* T3   = (const float*)d_in[4];
  const float* T4   = (const float*)d_in[5];
  const float* T5   = (const float*)d_in[6];
  const float* in_w = (const float*)d_in[7];
  const float* in_b = (const float*)d_in[8];
  const float* Wq   = (const float*)d_in[9];
  const float* Wk   = (const float*)d_in[10];
  const float* Wv   = (const float*)d_in[11];
  const float* Wo   = (const float*)d_in[12];
  const float* W1   = (const float*)d_in[13];
  const float* W2   = (const float*)d_in[14];
  const float* bq   = (const float*)d_in[15];
  const float* bk   = (const float*)d_in[16];
  const float* bv   = (const float*)d_in[17];
  const float* bo   = (const float*)d_in[18];
  const float* bf1  = (const float*)d_in[19];
  const float* bf2  = (const float*)d_in[20];
  const float* b1n  = (const float*)d_in[21];
  const float* b2n  = (const float*)d_in[22];
  const float* g1   = (const float*)d_in[23];
  const float* g2   = (const float*)d_in[24];
  const float* gf   = (const float*)d_in[25];
  const float* bfn  = (const float*)d_in[26];
  HeadPtrs hp;
  for (int i = 0; i < 6; ++i) {
    hp.pw[i] = (const float*)d_in[27 + i*4];
    hp.pb[i] = (const float*)d_in[28 + i*4];
    hp.vw[i] = (const float*)d_in[29 + i*4];
    hp.vb[i] = (const float*)d_in[30 + i*4];
  }

  float* ws   = (float*)d_ws;
  float* E    = ws;                 // 1024*1216
  float* h    = E    + 1245184;     // 1024*512
  float* q    = h    + 524288;
  float* k    = q    + 524288;
  float* v    = k    + 524288;
  float* attn = v    + 524288;
  float* a2   = attn + 524288;
  float* h2   = a2   + 524288;
  float* ff   = h2   + 524288;      // 1024*2048
  float* y    = ff   + 2097152;
  float* kvst = y    + 524288;      // 16*16*64*64
  float* ksum = kvst + 1048576;     // 16*16*64
  float* U    = ksum + 16384;
  float* Cc   = U    + 512;

  embed_gather<<<TOK, 256, 0, stream>>>(x, T0, T1, T2, T3, T4, T5, E);
  gemm_act<0><<<dim3(16, 8), 256, 0, stream>>>(E, in_w, in_b, h, TOK, 1216, DM);
  add_pos<<<TOK, 256, 0, stream>>>(h);

  for (int l = 0; l < 12; ++l) {
    const float* wq = Wq + (size_t)l*262144;
    const float* wk = Wk + (size_t)l*262144;
    const float* wv = Wv + (size_t)l*262144;
    const float* wo = Wo + (size_t)l*262144;
    const float* w1 = W1 + (size_t)l*1048576;
    const float* w2 = W2 + (size_t)l*1048576;
    gemm_act<1><<<dim3(16, 8), 256, 0, stream>>>(h, wq, bq + l*512, q, TOK, 512, 512);
    gemm_act<1><<<dim3(16, 8), 256, 0, stream>>>(h, wk, bk + l*512, k, TOK, 512, 512);
    gemm_act<0><<<dim3(16, 8), 256, 0, stream>>>(h, wv, bv + l*512, v, TOK, 512, 512);
    attn_chunk_sums<<<dim3(NCH, 16), 256, 0, stream>>>(k, v, kvst, ksum);
    attn_scan<<<16, 256, 0, stream>>>(kvst, ksum);
    attn_chunk_out<<<dim3(NCH, 16), 256, 0, stream>>>(q, k, v, kvst, ksum, attn);
    gemm_act<0><<<dim3(16, 8), 256, 0, stream>>>(attn, wo, bo + l*512, a2, TOK, 512, 512);
    resid_ln<<<TOK, 256, 0, stream>>>(h, a2, g1 + l*512, b1n + l*512, h2);
    gemm_act<2><<<dim3(16, 32), 256, 0, stream>>>(h2, w1, bf1 + l*2048, ff, TOK, 512, 2048);
    gemm_act<0><<<dim3(16, 8), 256, 0, stream>>>(ff, w2, bf2 + l*512, y, TOK, 2048, 512);
    resid_ln<<<TOK, 256, 0, stream>>>(h2, y, g2 + l*512, b2n + l*512, h);
  }

  resid_ln<<<TOK, 256, 0, stream>>>(h, nullptr, gf, bfn, h2);
  head_u<<<1, 512, 0, stream>>>(hp, U, Cc);
  final_out<<<NB, 512, 0, stream>>>(h2, U, Cc, (float*)d_out);
}

// Round 2
// 2068.748 us; speedup vs baseline: 3.5265x; 3.5265x over previous
//
#include <hip/hip_runtime.h>
#include <math.h>

typedef _Float16 f16;
typedef _Float16 f16x8 __attribute__((ext_vector_type(8)));
typedef float f32x4 __attribute__((ext_vector_type(4)));

#define TOK 1024   // B*S
#define DM  512
#define SEQ 512
#define NB  2
#define CHUNK 32
#define NCH (SEQ/CHUNK)   // 16

// ---------------- embedding gather ----------------
__global__ __launch_bounds__(256) void embed_gather(
    const int* __restrict__ x,
    const float* __restrict__ t0, const float* __restrict__ t1,
    const float* __restrict__ t2, const float* __restrict__ t3,
    const float* __restrict__ t4, const float* __restrict__ t5,
    float* __restrict__ E) {
  int t = blockIdx.x;
  int tid = threadIdx.x;
  const int* xb = x + t * 6;
  for (int c = tid; c < 1216; c += 256) {
    float val;
    if (c < 128)       val = t0[xb[0]*128 + c]        * 11.313708498984761f;
    else if (c < 384)  val = t1[xb[1]*256 + (c-128)]  * 16.0f;
    else if (c < 448)  val = t2[xb[2]*64  + (c-384)]  * 8.0f;
    else if (c < 960)  val = t3[xb[3]*512 + (c-448)]  * 22.627416997969522f;
    else if (c < 1088) val = t4[xb[4]*128 + (c-960)]  * 11.313708498984761f;
    else               val = t5[xb[5]*128 + (c-1088)] * 11.313708498984761f;
    E[(size_t)t*1216 + c] = val;
  }
}

// ---------------- positional encoding add ----------------
__global__ __launch_bounds__(256) void add_pos(float* __restrict__ h) {
  int t = blockIdx.x;
  int s = t & (SEQ-1);
  int tid = threadIdx.x;
  for (int d = tid; d < DM; d += 256) {
    int k = d >> 1;
    float div = expf((float)(2*k) * (-9.210340371976184f / 512.0f));
    float ang = (float)s * div;
    h[(size_t)t*DM + d] += (d & 1) ? cosf(ang) : sinf(ang);
  }
}

// ---------------- weight fp32 -> fp16 transpose-convert ----------------
// in: [K][N] fp32 (per-layer stride instride), out: [N][K] fp16 (stride outstride)
__global__ __launch_bounds__(256) void transp_convert(
    const float* __restrict__ in, f16* __restrict__ out,
    int K, int N, size_t instride, size_t outstride) {
  int lz = blockIdx.z;
  const float* I = in + (size_t)lz * instride;
  f16* O = out + (size_t)lz * outstride;
  __shared__ float tile[32][33];
  int k0 = blockIdx.x * 32, n0 = blockIdx.y * 32;
  int tid = threadIdx.x;
  int cr = tid >> 5, cc = tid & 31;
#pragma unroll
  for (int p = 0; p < 4; ++p)
    tile[cr + p*8][cc] = I[(size_t)(k0 + cr + p*8) * N + n0 + cc];
  __syncthreads();
#pragma unroll
  for (int p = 0; p < 4; ++p)
    O[(size_t)(n0 + cr + p*8) * K + k0 + cc] = (f16)tile[cc][cr + p*8];
}

// ---------------- fp16 MFMA GEMM + bias + activation ----------------
// C[M][N] = A[M][K] (fp32, converted on load) * Bt[N][K] (fp16, pre-transposed)
// E: 0 = bias only, 1 = bias + exact gelu, 2 = fused QKV epilogue
//    (E==2: cols 0-511 -> o0 with b0 + elu+1; 512-1023 -> o1 with b1 + elu+1;
//     1024-1535 -> o2 with b2, no act; each out has row stride 512)
template<int E>
__global__ __launch_bounds__(256) void mfma_gemm(
    const float* __restrict__ A, const f16* __restrict__ Bt,
    const float* __restrict__ b0, const float* __restrict__ b1,
    const float* __restrict__ b2,
    float* __restrict__ o0, float* __restrict__ o1, float* __restrict__ o2,
    int M, int K, int N) {
  __shared__ f16 As[64][40];   // +8 pad: 2-way-max bank aliasing on b128 reads
  __shared__ f16 Bs[64][40];
  const int tid = threadIdx.x;
  const int m0 = blockIdx.x * 64, n0 = blockIdx.y * 64;
  const int w = tid >> 6, l = tid & 63;
  const int wr = w >> 1, wc = w & 1;
  const int g = l >> 4, r = l & 15;
  const int lr = tid >> 2, lc = (tid & 3) * 8;
  f32x4 acc[2][2] = {};
  const float* Ap = A + (size_t)(m0 + lr) * K + lc;
  const f16*   Bp = Bt + (size_t)(n0 + lr) * K + lc;
  for (int k0 = 0; k0 < K; k0 += 32) {
    float4 av0 = *(const float4*)(Ap + k0);
    float4 av1 = *(const float4*)(Ap + k0 + 4);
    f16x8 a8;
    a8[0] = (f16)av0.x; a8[1] = (f16)av0.y; a8[2] = (f16)av0.z; a8[3] = (f16)av0.w;
    a8[4] = (f16)av1.x; a8[5] = (f16)av1.y; a8[6] = (f16)av1.z; a8[7] = (f16)av1.w;
    *(f16x8*)&As[lr][lc] = a8;
    *(f16x8*)&Bs[lr][lc] = *(const f16x8*)(Bp + k0);
    __syncthreads();
    f16x8 af0 = *(const f16x8*)&As[wr*32 + r][g*8];
    f16x8 af1 = *(const f16x8*)&As[wr*32 + 16 + r][g*8];
    f16x8 bf0 = *(const f16x8*)&Bs[wc*32 + r][g*8];
    f16x8 bf1v = *(const f16x8*)&Bs[wc*32 + 16 + r][g*8];
    acc[0][0] = __builtin_amdgcn_mfma_f32_16x16x32_f16(af0, bf0, acc[0][0], 0, 0, 0);
    acc[0][1] = __builtin_amdgcn_mfma_f32_16x16x32_f16(af0, bf1v, acc[0][1], 0, 0, 0);
    acc[1][0] = __builtin_amdgcn_mfma_f32_16x16x32_f16(af1, bf0, acc[1][0], 0, 0, 0);
    acc[1][1] = __builtin_amdgcn_mfma_f32_16x16x32_f16(af1, bf1v, acc[1][1], 0, 0, 0);
    __syncthreads();
  }
#pragma unroll
  for (int m = 0; m < 2; ++m) {
    int row = m0 + wr*32 + m*16 + g*4;
#pragma unroll
    for (int n = 0; n < 2; ++n) {
      int col = n0 + wc*32 + n*16 + r;
#pragma unroll
      for (int i = 0; i < 4; ++i) {
        float v = acc[m][n][i];
        if (E == 2) {
          int which = col >> 9;
          int lc2 = col & 511;
          const float* bb = (which == 0) ? b0 : (which == 1) ? b1 : b2;
          float* oo = (which == 0) ? o0 : (which == 1) ? o1 : o2;
          v += bb[lc2];
          if (which < 2) v = (v > 0.0f) ? v + 1.0f : expf(v);
          oo[(size_t)(row + i) * 512 + lc2] = v;
        } else {
          v += b0[col];
          if (E == 1) v = 0.5f * v * (1.0f + erff(v * 0.70710678118654752f));
          o0[(size_t)(row + i) * N + col] = v;
        }
      }
    }
  }
}

// ---------------- attention pass A: per-chunk KV / K sums ----------------
__global__ __launch_bounds__(256) void attn_chunk_sums(
    const float* __restrict__ Kg, const float* __restrict__ Vg,
    float* __restrict__ kvst, float* __restrict__ ksum) {
  int ch = blockIdx.x, bh = blockIdx.y;
  int b = bh >> 3, h = bh & 7;
  __shared__ float Ks[CHUNK][64], Vs[CHUNK][64];
  int tid = threadIdx.x;
  const float* Kbase = Kg + ((size_t)(b*SEQ + ch*CHUNK))*DM + h*64;
  const float* Vbase = Vg + ((size_t)(b*SEQ + ch*CHUNK))*DM + h*64;
#pragma unroll
  for (int l = 0; l < CHUNK*64/256; ++l) {
    int e = tid + l*256;
    int r = e >> 6, c = e & 63;
    Ks[r][c] = Kbase[(size_t)r*DM + c];
    Vs[r][c] = Vbase[(size_t)r*DM + c];
  }
  __syncthreads();
  int d = tid >> 2, m0 = (tid & 3) * 16;
  float acc[16] = {};
  for (int s = 0; s < CHUNK; ++s) {
    float kd = Ks[s][d];
#pragma unroll
    for (int j = 0; j < 16; ++j) acc[j] += kd * Vs[s][m0+j];
  }
  float* dst = kvst + (((size_t)(bh*NCH + ch)*64 + d)*64) + m0;
#pragma unroll
  for (int j = 0; j < 16; ++j) dst[j] = acc[j];
  if (tid < 64) {
    float s = 0;
    for (int r = 0; r < CHUNK; ++r) s += Ks[r][tid];
    ksum[(size_t)(bh*NCH + ch)*64 + tid] = s;
  }
}

// ---------------- attention pass B: exclusive prefix over chunks ----------------
__global__ __launch_bounds__(256) void attn_scan(
    float* __restrict__ kvst, float* __restrict__ ksum) {
  int bh = blockIdx.x;
  int tid = threadIdx.x;
  for (int l = 0; l < 16; ++l) {
    int e = tid + l*256;
    float run = 0.0f;
    size_t base = (size_t)bh*NCH*4096 + e;
    for (int ch = 0; ch < NCH; ++ch) {
      size_t idx = base + (size_t)ch*4096;
      float t = kvst[idx];
      kvst[idx] = run;
      run += t;
    }
  }
  if (tid < 64) {
    float run = 0.0f;
    for (int ch = 0; ch < NCH; ++ch) {
      size_t idx = (size_t)(bh*NCH + ch)*64 + tid;
      float t = ksum[idx];
      ksum[idx] = run;
      run += t;
    }
  }
}

// ---------------- attention pass C: per-chunk output ----------------
__global__ __launch_bounds__(256) void attn_chunk_out(
    const float* __restrict__ Qg, const float* __restrict__ Kg,
    const float* __restrict__ Vg, const float* __restrict__ kvst,
    const float* __restrict__ ksum, float* __restrict__ O) {
  int ch = blockIdx.x, bh = blockIdx.y;
  int b = bh >> 3, h = bh & 7;
  __shared__ float Qs[CHUNK][64], Ks[CHUNK][64], Vs[CHUNK][64];
  __shared__ float kvp[64][64];
  __shared__ float Sl[CHUNK][CHUNK+1];
  __shared__ float ksp[64];
  __shared__ float den[CHUNK];
  int tid = threadIdx.x;
  const float* Qbase = Qg + ((size_t)(b*SEQ + ch*CHUNK))*DM + h*64;
  const float* Kbase = Kg + ((size_t)(b*SEQ + ch*CHUNK))*DM + h*64;
  const float* Vbase = Vg + ((size_t)(b*SEQ + ch*CHUNK))*DM + h*64;
#pragma unroll
  for (int l = 0; l < CHUNK*64/256; ++l) {
    int e = tid + l*256;
    int r = e >> 6, c = e & 63;
    Qs[r][c] = Qbase[(size_t)r*DM + c];
    Ks[r][c] = Kbase[(size_t)r*DM + c];
    Vs[r][c] = Vbase[(size_t)r*DM + c];
  }
  {
    const float* src = kvst + (size_t)(bh*NCH + ch)*4096;
#pragma unroll
    for (int l = 0; l < 16; ++l) {
      int e = tid + l*256;
      ((float*)kvp)[e] = src[e];
    }
  }
  if (tid < 64) ksp[tid] = ksum[(size_t)(bh*NCH + ch)*64 + tid];
  __syncthreads();
#pragma unroll
  for (int l = 0; l < 4; ++l) {
    int e = tid + l*256;
    int i = e >> 5, j = e & 31;
    float s = 0;
    for (int d2 = 0; d2 < 64; ++d2) s += Qs[i][d2] * Ks[j][d2];
    Sl[i][j] = s;
  }
  __syncthreads();
  if (tid < CHUNK) {
    int i = tid;
    float dsum = 0;
    for (int d2 = 0; d2 < 64; ++d2) dsum += Qs[i][d2] * ksp[d2];
    for (int j = 0; j <= i; ++j) dsum += Sl[i][j];
    den[i] = 1.0f / (dsum + 1e-6f);
  }
  __syncthreads();
  int row = tid >> 3, m0 = (tid & 7) * 8;
  float acc[8] = {};
  for (int d2 = 0; d2 < 64; ++d2) {
    float qd = Qs[row][d2];
#pragma unroll
    for (int j = 0; j < 8; ++j) acc[j] += qd * kvp[d2][m0+j];
  }
  for (int j2 = 0; j2 <= row; ++j2) {
    float sv = Sl[row][j2];
#pragma unroll
    for (int j = 0; j < 8; ++j) acc[j] += sv * Vs[j2][m0+j];
  }
  float zi = den[row];
  float* dst = O + ((size_t)(b*SEQ + ch*CHUNK + row))*DM + h*64 + m0;
#pragma unroll
  for (int j = 0; j < 8; ++j) dst[j] = acc[j] * zi;
}

// ---------------- residual + layernorm ----------------
__global__ __launch_bounds__(256) void resid_ln(
    const float* __restrict__ x, const float* __restrict__ r,
    const float* __restrict__ g, const float* __restrict__ bb,
    float* __restrict__ out) {
  int t = blockIdx.x;
  int tid = threadIdx.x;
  __shared__ float red[256];
  const float* xb = x + (size_t)t*DM;
  float v0 = xb[tid];
  float v1 = xb[tid+256];
  if (r) {
    const float* rb = r + (size_t)t*DM;
    v0 += rb[tid];
    v1 += rb[tid+256];
  }
  red[tid] = v0 + v1;
  __syncthreads();
  for (int o = 128; o > 0; o >>= 1) {
    if (tid < o) red[tid] += red[tid+o];
    __syncthreads();
  }
  float mean = red[0] * (1.0f/512.0f);
  __syncthreads();
  float d0 = v0 - mean, d1 = v1 - mean;
  red[tid] = d0*d0 + d1*d1;
  __syncthreads();
  for (int o = 128; o > 0; o >>= 1) {
    if (tid < o) red[tid] += red[tid+o];
    __syncthreads();
  }
  float rs = rsqrtf(red[0] * (1.0f/512.0f) + 1e-5f);
  out[(size_t)t*DM + tid]     = d0*rs*g[tid]     + bb[tid];
  out[(size_t)t*DM + tid+256] = d1*rs*g[tid+256] + bb[tid+256];
}

// ---------------- collapsed output heads ----------------
struct HeadPtrs {
  const float* pw[6]; const float* pb[6];
  const float* vw[6]; const float* vb[6];
};

__global__ __launch_bounds__(512) void head_u(HeadPtrs hp, float* __restrict__ U,
                                              float* __restrict__ Cc) {
  const int vsz[6] = {56, 135, 18, 87, 18, 25};
  int d = threadIdx.x;
  float acc = 0;
  for (int i = 0; i < 6; ++i) {
    const float* pwrow = hp.pw[i] + (size_t)d * vsz[i];
    const float* vwi = hp.vw[i];
    for (int j = 0; j < vsz[i]; ++j) acc += pwrow[j] * vwi[j];
  }
  U[d] = acc;
  if (d == 0) {
    float c = 0;
    for (int i = 0; i < 6; ++i) {
      float cc = hp.vb[i][0];
      for (int j = 0; j < vsz[i]; ++j) cc += hp.pb[i][j] * hp.vw[i][j];
      c += cc;
    }
    Cc[0] = c;
  }
}

__global__ __launch_bounds__(512) void final_out(
    const float* __restrict__ hf, const float* __restrict__ U,
    const float* __restrict__ Cc, float* __restrict__ out) {
  int b = blockIdx.x;
  int d = threadIdx.x;
  __shared__ float red[512];
  float cs = 0;
  const float* hb = hf + (size_t)b*SEQ*DM + d;
  for (int s = 0; s < SEQ; ++s) cs += hb[(size_t)s*DM];
  red[d] = cs * U[d];
  __syncthreads();
  for (int o = 256; o > 0; o >>= 1) {
    if (d < o) red[d] += red[d+o];
    __syncthreads();
  }
  if (d == 0) out[b] = (red[0] * (1.0f/512.0f) + Cc[0]) * (1.0f/6.0f);
}

// ---------------- launch ----------------
extern "C" void kernel_launch(void* const* d_in, const int* in_sizes, int n_in,
                              void* d_out, int out_size, void* d_ws, size_t ws_size,
                              hipStream_t stream) {
  const int*   x    = (const int*)d_in[0];
  const float* T0   = (const float*)d_in[1];
  const float* T1   = (const float*)d_in[2];
  const float* T2   = (const float*)d_in[3];
  const float* T3   = (const float*)d_in[4];
  const float* T4   = (const float*)d_in[5];
  const float* T5   = (const float*)d_in[6];
  const float* in_w = (const float*)d_in[7];
  const float* in_b = (const float*)d_in[8];
  const float* Wq   = (const float*)d_in[9];
  const float* Wk   = (const float*)d_in[10];
  const float* Wv   = (const float*)d_in[11];
  const float* Wo   = (const float*)d_in[12];
  const float* W1   = (const float*)d_in[13];
  const float* W2   = (const float*)d_in[14];
  const float* bq   = (const float*)d_in[15];
  const float* bk   = (const float*)d_in[16];
  const float* bv   = (const float*)d_in[17];
  const float* bo   = (const float*)d_in[18];
  const float* bf1  = (const float*)d_in[19];
  const float* bf2  = (const float*)d_in[20];
  const float* b1n  = (const float*)d_in[21];
  const float* b2n  = (const float*)d_in[22];
  const float* g1   = (const float*)d_in[23];
  const float* g2   = (const float*)d_in[24];
  const float* gf   = (const float*)d_in[25];
  const float* bfn  = (const float*)d_in[26];
  HeadPtrs hp;
  for (int i = 0; i < 6; ++i) {
    hp.pw[i] = (const float*)d_in[27 + i*4];
    hp.pb[i] = (const float*)d_in[28 + i*4];
    hp.vw[i] = (const float*)d_in[29 + i*4];
    hp.vb[i] = (const float*)d_in[30 + i*4];
  }

  float* ws   = (float*)d_ws;
  float* E_   = ws;                 // 1024*1216
  float* h    = E_   + 1245184;
  float* q    = h    + 524288;
  float* k    = q    + 524288;
  float* v    = k    + 524288;
  float* attn = v    + 524288;
  float* a2   = attn + 524288;
  float* h2   = a2   + 524288;
  float* ff   = h2   + 524288;      // 1024*2048
  float* y    = ff   + 2097152;
  float* kvst = y    + 524288;      // 16*16*64*64
  float* ksum = kvst + 1048576;     // 16*16*64
  float* U    = ksum + 16384;
  float* Cc   = U    + 512;
  f16* in_wt  = (f16*)(Cc + 16);    // 512*1216
  f16* qkvw   = in_wt + 623616;     // 12*1536*512 (rows: Wq^T | Wk^T | Wv^T)
  f16* wot    = qkvw + 9437184;     // 12*512*512
  f16* w1t    = wot + 3145728;      // 12*2048*512
  f16* w2t    = w1t + 12582912;     // 12*512*2048

  // weight conversion (per call; ~230 MB traffic)
  transp_convert<<<dim3(38,16,1),  256, 0, stream>>>(in_w, in_wt, 1216, 512, 0, 0);
  transp_convert<<<dim3(16,16,12), 256, 0, stream>>>(Wq, qkvw,          512, 512, 262144, 786432);
  transp_convert<<<dim3(16,16,12), 256, 0, stream>>>(Wk, qkvw + 262144, 512, 512, 262144, 786432);
  transp_convert<<<dim3(16,16,12), 256, 0, stream>>>(Wv, qkvw + 524288, 512, 512, 262144, 786432);
  transp_convert<<<dim3(16,16,12), 256, 0, stream>>>(Wo, wot,           512, 512, 262144, 262144);
  transp_convert<<<dim3(16,64,12), 256, 0, stream>>>(W1, w1t,  512, 2048, 1048576, 1048576);
  transp_convert<<<dim3(64,16,12), 256, 0, stream>>>(W2, w2t, 2048,  512, 1048576, 1048576);

  embed_gather<<<TOK, 256, 0, stream>>>(x, T0, T1, T2, T3, T4, T5, E_);
  mfma_gemm<0><<<dim3(16,8), 256, 0, stream>>>(E_, in_wt, in_b, nullptr, nullptr,
                                               h, nullptr, nullptr, TOK, 1216, 512);
  add_pos<<<TOK, 256, 0, stream>>>(h);

  for (int l = 0; l < 12; ++l) {
    mfma_gemm<2><<<dim3(16,24), 256, 0, stream>>>(h, qkvw + (size_t)l*786432,
        bq + l*512, bk + l*512, bv + l*512, q, k, v, TOK, 512, 1536);
    attn_chunk_sums<<<dim3(NCH,16), 256, 0, stream>>>(k, v, kvst, ksum);
    attn_scan<<<16, 256, 0, stream>>>(kvst, ksum);
    attn_chunk_out<<<dim3(NCH,16), 256, 0, stream>>>(q, k, v, kvst, ksum, attn);
    mfma_gemm<0><<<dim3(16,8), 256, 0, stream>>>(attn, wot + (size_t)l*262144,
        bo + l*512, nullptr, nullptr, a2, nullptr, nullptr, TOK, 512, 512);
    resid_ln<<<TOK, 256, 0, stream>>>(h, a2, g1 + l*512, b1n + l*512, h2);
    mfma_gemm<1><<<dim3(16,32), 256, 0, stream>>>(h2, w1t + (size_t)l*1048576,
        bf1 + l*2048, nullptr, nullptr, ff, nullptr, nullptr, TOK, 512, 2048);
    mfma_gemm<0><<<dim3(16,8), 256, 0, stream>>>(ff, w2t + (size_t)l*1048576,
        bf2 + l*512, nullptr, nullptr, y, nullptr, nullptr, TOK, 2048, 512);
    resid_ln<<<TOK, 256, 0, stream>>>(h2, y, g2 + l*512, b2n + l*512, h);
  }

  resid_ln<<<TOK, 256, 0, stream>>>(h, nullptr, gf, bfn, h2);
  head_u<<<1, 512, 0, stream>>>(hp, U, Cc);
  final_out<<<NB, 512, 0, stream>>>(h2, U, Cc, (float*)d_out);
}